// Round 2
// baseline (1080.316 us; speedup 1.0000x reference)
//
#include <hip/hip_runtime.h>
#include <hip/hip_bf16.h>
#include <cfloat>

#define NN 50000
#define EE 800000
#define FD 128
#define NL 10
#define NTOT 100000   // 2 runs * NN

__device__ __forceinline__ float wave_red_sum(float v){
  #pragma unroll
  for (int o=1;o<64;o<<=1) v += __shfl_xor(v,o,64);
  return v;
}
__device__ __forceinline__ float wave_red_max(float v){
  #pragma unroll
  for (int o=1;o<64;o<<=1) v = fmaxf(v,__shfl_xor(v,o,64));
  return v;
}

// drop mask, drop_b output (f32), deg/cursor init
__global__ __launch_bounds__(256) void k_prep(const float* __restrict__ dh, float* __restrict__ mask,
                                              int* __restrict__ deg, int* __restrict__ cur,
                                              float* __restrict__ out){
  int i = blockIdx.x*256 + threadIdx.x;
  if (i >= NN) return;
  float m = (dh[i] + dh[NN+i] + dh[2*NN+i] + dh[3*NN+i]) * 0.25f;
  bool dropped = (m != 0.0f);
  mask[i] = dropped ? 0.0f : 1.0f;
  deg[i] = 1;            // self loop
  cur[i] = 0;
  out[i]      = dropped ? 1.0f : 0.0f;  // run 0 drop_b
  out[NN + i] = 0.0f;                   // run 1 drop_b (bernoulli p=0)
}

__global__ __launch_bounds__(256) void k_hist(const int* __restrict__ dst, int* __restrict__ deg){
  int e = blockIdx.x*256 + threadIdx.x;
  if (e < EE) atomicAdd(&deg[dst[e]], 1);
}

// exclusive scan of deg -> rowp, single block of 1024
__global__ __launch_bounds__(1024) void k_scan(const int* __restrict__ deg, int* __restrict__ rowp){
  __shared__ int wsum[16];
  __shared__ int carry;
  int tid = threadIdx.x, lane = tid & 63, wid = tid >> 6;
  if (tid == 0) carry = 0;
  __syncthreads();
  for (int base = 0; base < NN; base += 1024){
    int idx = base + tid;
    int v = (idx < NN) ? deg[idx] : 0;
    int x = v;
    #pragma unroll
    for (int o=1;o<64;o<<=1){ int t = __shfl_up(x,o,64); if (lane >= o) x += t; }
    if (lane == 63) wsum[wid] = x;
    __syncthreads();
    if (wid == 0){
      int t = (lane < 16) ? wsum[lane] : 0;
      #pragma unroll
      for (int o=1;o<16;o<<=1){ int u = __shfl_up(t,o,64); if (lane >= o) t += u; }
      if (lane < 16) wsum[lane] = t;
    }
    __syncthreads();
    int wexcl = wid ? wsum[wid-1] : 0;
    int incl = x + wexcl;
    int c = carry;
    if (idx < NN) rowp[idx] = c + incl - v;
    __syncthreads();
    if (tid == 1023) carry = c + wsum[15];
    __syncthreads();
  }
  if (threadIdx.x == 0) rowp[NN] = carry;
}

// fill CSR (self loops + edges), compute dinv
__global__ __launch_bounds__(256) void k_fill(const int* __restrict__ src, const int* __restrict__ dst,
                                              const int* __restrict__ rowp, int* __restrict__ cur,
                                              const int* __restrict__ deg, float* __restrict__ dinv,
                                              int* __restrict__ colv){
  int t = blockIdx.x*256 + threadIdx.x;
  if (t < NN){
    dinv[t] = rsqrtf((float)deg[t]);
    int pos = rowp[t] + atomicAdd(&cur[t], 1);
    colv[pos] = t;                       // self loop
  } else if (t < NN + EE){
    int e = t - NN;
    int d = dst[e];
    int pos = rowp[d] + atomicAdd(&cur[d], 1);
    colv[pos] = src[e];
  }
}

// C[nrows x 128] = X @ W ; W staged in 64KB dynamic LDS; 16 rows per wave,
// X fed through wave-uniform (scalar) loads.
__global__ __launch_bounds__(256) void k_gemm128(const float* __restrict__ X, const float* __restrict__ W,
                                                 float* __restrict__ C, int nrows){
  extern __shared__ float Wl[];   // 128*128 floats
  int tid = threadIdx.x;
  #pragma unroll
  for (int i=0;i<16;i++){
    int idx = (i*256 + tid)*4;
    *(float4*)&Wl[idx] = *(const float4*)&W[idx];
  }
  __syncthreads();
  int lane = tid & 63;
  int wid = __builtin_amdgcn_readfirstlane(tid >> 6);
  int row0 = blockIdx.x*64 + wid*16;
  int c2 = lane*2;
  float acc[16][2];
  #pragma unroll
  for (int r=0;r<16;r++){ acc[r][0]=0.f; acc[r][1]=0.f; }
  const float* xp = X + (size_t)row0*FD;
  if (row0 + 16 <= nrows){
    #pragma unroll 4
    for (int k=0;k<FD;k++){
      float2 w = *(float2*)&Wl[k*FD + c2];
      #pragma unroll
      for (int r=0;r<16;r++){
        float xv = xp[r*FD + k];
        acc[r][0] += xv*w.x; acc[r][1] += xv*w.y;
      }
    }
  } else {
    int nr = nrows - row0; if (nr < 0) nr = 0; if (nr > 16) nr = 16;
    for (int k=0;k<FD;k++){
      float2 w = *(float2*)&Wl[k*FD + c2];
      for (int r=0;r<16;r++){
        if (r < nr){
          float xv = xp[r*FD + k];
          acc[r][0] += xv*w.x; acc[r][1] += xv*w.y;
        }
      }
    }
  }
  #pragma unroll
  for (int r=0;r<16;r++){
    int row = row0 + r;
    if (row < nrows) *(float2*)&C[(size_t)row*FD + c2] = make_float2(acc[r][0], acc[r][1]);
  }
}

// buf[0..N) holds XW; write run1 copy at [N..2N), scale run0 rows by mask in place
__global__ __launch_bounds__(256) void k_expand(float* __restrict__ buf, const float* __restrict__ mask){
  int t = blockIdx.x*256 + threadIdx.x;     // float4 index over N*128
  if (t >= NN*32) return;
  int node = t >> 5;
  float4 v = *(float4*)&buf[(size_t)t*4];
  *(float4*)&buf[(size_t)(NN*32 + t)*4] = v;     // run 1 (no drop)
  float m = mask[node];
  if (m != 1.0f){ v.x*=m; v.y*=m; v.z*=m; v.w*=m; *(float4*)&buf[(size_t)t*4] = v; }
}

// per-row dot with att_src / att_dst
__global__ __launch_bounds__(256) void k_alpha(const float* __restrict__ H, const float* __restrict__ av,
                                               const float* __restrict__ bv, float* __restrict__ asv,
                                               float* __restrict__ adv){
  int w = blockIdx.x*4 + (threadIdx.x >> 6);
  int lane = threadIdx.x & 63;
  float2 h = *(const float2*)&H[(size_t)w*FD + lane*2];
  float2 a = *(const float2*)&av[lane*2];
  float2 b = *(const float2*)&bv[lane*2];
  float ps = h.x*a.x + h.y*a.y;
  float pd = h.x*b.x + h.y*b.y;
  ps = wave_red_sum(ps); pd = wave_red_sum(pd);
  if (lane == 0){ asv[w] = ps; adv[w] = pd; }
}

// GCN aggregation: wave per (run,dst); out = relu(sum norm*h[s] + b)
__global__ __launch_bounds__(256) void k_gcn_agg(const float* __restrict__ H, const int* __restrict__ rowp,
                                                 const int* __restrict__ colv, const float* __restrict__ dinv,
                                                 const float* __restrict__ bias, float* __restrict__ O){
  int w = blockIdx.x*4 + (threadIdx.x >> 6);
  int lane = threadIdx.x & 63;
  int r = (w >= NN);
  int i = w - r*NN;
  const float* base = H + (size_t)r*NN*FD;
  float di = dinv[i];
  float ax = 0.f, ay = 0.f;
  int e0 = rowp[i], e1 = rowp[i+1];
  for (int j=e0; j<e1; j++){
    int s = colv[j];
    float nw = di*dinv[s];
    float2 h = *(const float2*)&base[(size_t)s*FD + lane*2];
    ax += nw*h.x; ay += nw*h.y;
  }
  float2 b = *(const float2*)&bias[lane*2];
  ax = fmaxf(ax + b.x, 0.f); ay = fmaxf(ay + b.y, 0.f);
  *(float2*)&O[(size_t)w*FD + lane*2] = make_float2(ax, ay);
}

// GAT aggregation: wave per (run,dst); edge softmax over in-edges
__global__ __launch_bounds__(256) void k_gat_agg(const float* __restrict__ H, const int* __restrict__ rowp,
                                                 const int* __restrict__ colv, const float* __restrict__ asv,
                                                 const float* __restrict__ adv, const float* __restrict__ bias,
                                                 float* __restrict__ O){
  int w = blockIdx.x*4 + (threadIdx.x >> 6);
  int lane = threadIdx.x & 63;
  int r = (w >= NN);
  int i = w - r*NN;
  int goff = r*NN;
  float adi = adv[w];
  int e0 = rowp[i], e1 = rowp[i+1];
  float m = -FLT_MAX;
  for (int j=e0+lane; j<e1; j+=64){
    float e = asv[goff + colv[j]] + adi;
    e = (e > 0.f) ? e : 0.2f*e;
    m = fmaxf(m, e);
  }
  m = wave_red_max(m);
  float dsum = 0.f;
  for (int j=e0+lane; j<e1; j+=64){
    float e = asv[goff + colv[j]] + adi;
    e = (e > 0.f) ? e : 0.2f*e;
    dsum += __expf(e - m);
  }
  dsum = wave_red_sum(dsum);
  float inv = 1.0f / dsum;
  const float* base = H + (size_t)r*NN*FD;
  float ax = 0.f, ay = 0.f;
  for (int j=e0; j<e1; j++){
    int s = colv[j];
    float e = asv[goff + s] + adi;
    e = (e > 0.f) ? e : 0.2f*e;
    float wgt = __expf(e - m);
    float2 h = *(const float2*)&base[(size_t)s*FD + lane*2];
    ax += wgt*h.x; ay += wgt*h.y;
  }
  float2 b = *(const float2*)&bias[lane*2];
  ax = fmaxf(ax*inv + b.x, 0.f); ay = fmaxf(ay*inv + b.y, 0.f);
  *(float2*)&O[(size_t)w*FD + lane*2] = make_float2(ax, ay);
}

// P[ntot x 10] = H @ W2 via wave reductions
__global__ __launch_bounds__(256) void k_gemm10(const float* __restrict__ H, const float* __restrict__ W2,
                                                float* __restrict__ P){
  int w = blockIdx.x*4 + (threadIdx.x >> 6);
  int lane = threadIdx.x & 63;
  float2 h = *(const float2*)&H[(size_t)w*FD + lane*2];
  const float* w0 = &W2[(2*lane)*NL];
  const float* w1 = &W2[(2*lane+1)*NL];
  float a[NL];
  #pragma unroll
  for (int l=0;l<NL;l++){
    float p = h.x*w0[l] + h.y*w1[l];
    a[l] = wave_red_sum(p);
  }
  if (lane == 0){
    #pragma unroll
    for (int l=0;l<NL;l++) P[(size_t)w*NL + l] = a[l];
  }
}

// GCN2 aggregation + bias + log_softmax + f32 store
__global__ __launch_bounds__(256) void k_final(const float* __restrict__ P, const int* __restrict__ rowp,
                                               const int* __restrict__ colv, const float* __restrict__ dinv,
                                               const float* __restrict__ b2, float* __restrict__ out){
  int g = blockIdx.x*256 + threadIdx.x;
  if (g >= NTOT) return;
  int r = (g >= NN);
  int i = g - r*NN;
  float di = dinv[i];
  const float* base = P + (size_t)r*NN*NL;
  float acc[NL];
  #pragma unroll
  for (int l=0;l<NL;l++) acc[l] = 0.f;
  int e0 = rowp[i], e1 = rowp[i+1];
  for (int j=e0; j<e1; j++){
    int s = colv[j];
    float nw = di*dinv[s];
    const float* ps = &base[(size_t)s*NL];
    #pragma unroll
    for (int l=0;l<NL;l++) acc[l] += nw*ps[l];
  }
  float mx = -FLT_MAX;
  #pragma unroll
  for (int l=0;l<NL;l++){ acc[l] += b2[l]; mx = fmaxf(mx, acc[l]); }
  float s = 0.f;
  #pragma unroll
  for (int l=0;l<NL;l++) s += __expf(acc[l]-mx);
  float lse = mx + __logf(s);
  #pragma unroll
  for (int l=0;l<NL;l++) out[(size_t)NTOT + (size_t)g*NL + l] = acc[l]-lse;
}

extern "C" void kernel_launch(void* const* d_in, const int* in_sizes, int n_in,
                              void* d_out, int out_size, void* d_ws, size_t ws_size,
                              hipStream_t stream){
  const float* x    = (const float*)d_in[0];
  const int*   ei   = (const int*)  d_in[1];
  const float* dh   = (const float*)d_in[2];
  const float* W1   = (const float*)d_in[3];
  const float* b1   = (const float*)d_in[4];
  const float* Wg   = (const float*)d_in[5];
  const float* asrc = (const float*)d_in[6];
  const float* adst = (const float*)d_in[7];
  const float* bg   = (const float*)d_in[8];
  const float* W2   = (const float*)d_in[9];
  const float* b2   = (const float*)d_in[10];
  float* out = (float*)d_out;

  char* ws = (char*)d_ws;
  size_t off = 0;
  auto alloc = [&](size_t bytes)->void*{ void* p = ws + off; off = (off + bytes + 255) & ~(size_t)255; return p; };
  int*   deg  = (int*)  alloc((size_t)NN*4);
  int*   rowp = (int*)  alloc((size_t)(NN+1)*4);
  int*   cur  = (int*)  alloc((size_t)NN*4);
  float* dinv = (float*)alloc((size_t)NN*4);
  float* mask = (float*)alloc((size_t)NN*4);
  int*   colv = (int*)  alloc((size_t)(EE+NN)*4);
  float* bufA = (float*)alloc((size_t)NTOT*FD*4);
  float* bufB = (float*)alloc((size_t)NTOT*FD*4);
  float* asv  = (float*)alloc((size_t)NTOT*4);
  float* adv  = (float*)alloc((size_t)NTOT*4);
  float* p10  = (float*)alloc((size_t)NTOT*NL*4);

  const int* srcp = ei;
  const int* dstp = ei + EE;

  k_prep<<<(NN+255)/256, 256, 0, stream>>>(dh, mask, deg, cur, out);
  k_hist<<<(EE+255)/256, 256, 0, stream>>>(dstp, deg);
  k_scan<<<1, 1024, 0, stream>>>(deg, rowp);
  k_fill<<<(NN+EE+255)/256, 256, 0, stream>>>(srcp, dstp, rowp, cur, deg, dinv, colv);

  // layer 1: GCN  (GEMM on N rows, expand to both runs with mask)
  k_gemm128<<<(NN+63)/64, 256, 65536, stream>>>(x, W1, bufA, NN);
  k_expand<<<(NN*32)/256, 256, 0, stream>>>(bufA, mask);
  k_gcn_agg<<<NTOT/4, 256, 0, stream>>>(bufA, rowp, colv, dinv, b1, bufB);

  // layer 2: GAT
  k_gemm128<<<(NTOT+63)/64, 256, 65536, stream>>>(bufB, Wg, bufA, NTOT);
  k_alpha<<<NTOT/4, 256, 0, stream>>>(bufA, asrc, adst, asv, adv);
  k_gat_agg<<<NTOT/4, 256, 0, stream>>>(bufA, rowp, colv, asv, adv, bg, bufB);

  // layer 3: GAT
  k_gemm128<<<(NTOT+63)/64, 256, 65536, stream>>>(bufB, Wg, bufA, NTOT);
  k_alpha<<<NTOT/4, 256, 0, stream>>>(bufA, asrc, adst, asv, adv);
  k_gat_agg<<<NTOT/4, 256, 0, stream>>>(bufA, rowp, colv, asv, adv, bg, bufB);

  // layer 4: GCN(128->10) + log_softmax
  k_gemm10<<<NTOT/4, 256, 0, stream>>>(bufB, W2, p10);
  k_final<<<(NTOT+255)/256, 256, 0, stream>>>(p10, rowp, colv, dinv, b2, out);
}

// Round 3
// 1031.261 us; speedup vs baseline: 1.0476x; 1.0476x over previous
//
#include <hip/hip_runtime.h>
#include <hip/hip_bf16.h>
#include <cfloat>

#define NN 50000
#define EE 800000
#define FD 128
#define NL 10
#define NTOT 100000   // 2 runs * NN

typedef unsigned short ushort_t;
typedef unsigned int uint_t;

__device__ __forceinline__ float wave_red_sum(float v){
  #pragma unroll
  for (int o=1;o<64;o<<=1) v += __shfl_xor(v,o,64);
  return v;
}
__device__ __forceinline__ float wave_red_max(float v){
  #pragma unroll
  for (int o=1;o<64;o<<=1) v = fmaxf(v,__shfl_xor(v,o,64));
  return v;
}

// bf16 helpers (RTNE pack, bit unpack)
__device__ __forceinline__ ushort_t f2bf(float f){
  uint_t i = __float_as_uint(f);
  uint_t r = i + 0x7fffu + ((i>>16)&1u);
  return (ushort_t)(r>>16);
}
__device__ __forceinline__ uint_t pack_bf2(float x, float y){
  return (uint_t)f2bf(x) | ((uint_t)f2bf(y)<<16);
}
__device__ __forceinline__ float2 unpack_bf2(uint_t v){
  float2 r;
  r.x = __uint_as_float((v & 0xffffu) << 16);
  r.y = __uint_as_float(v & 0xffff0000u);
  return r;
}

// drop mask, drop_b output (f32), deg/cursor init
__global__ __launch_bounds__(256) void k_prep(const float* __restrict__ dh, float* __restrict__ mask,
                                              int* __restrict__ deg, int* __restrict__ cur,
                                              float* __restrict__ out){
  int i = blockIdx.x*256 + threadIdx.x;
  if (i >= NN) return;
  float m = (dh[i] + dh[NN+i] + dh[2*NN+i] + dh[3*NN+i]) * 0.25f;
  bool dropped = (m != 0.0f);
  mask[i] = dropped ? 0.0f : 1.0f;
  deg[i] = 1;            // self loop
  cur[i] = 0;
  out[i]      = dropped ? 1.0f : 0.0f;  // run 0 drop_b
  out[NN + i] = 0.0f;                   // run 1 drop_b (bernoulli p=0)
}

__global__ __launch_bounds__(256) void k_hist(const int* __restrict__ dst, int* __restrict__ deg){
  int e = blockIdx.x*256 + threadIdx.x;
  if (e < EE) atomicAdd(&deg[dst[e]], 1);
}

// exclusive scan of deg -> rowp, single block of 1024
__global__ __launch_bounds__(1024) void k_scan(const int* __restrict__ deg, int* __restrict__ rowp){
  __shared__ int wsum[16];
  __shared__ int carry;
  int tid = threadIdx.x, lane = tid & 63, wid = tid >> 6;
  if (tid == 0) carry = 0;
  __syncthreads();
  for (int base = 0; base < NN; base += 1024){
    int idx = base + tid;
    int v = (idx < NN) ? deg[idx] : 0;
    int x = v;
    #pragma unroll
    for (int o=1;o<64;o<<=1){ int t = __shfl_up(x,o,64); if (lane >= o) x += t; }
    if (lane == 63) wsum[wid] = x;
    __syncthreads();
    if (wid == 0){
      int t = (lane < 16) ? wsum[lane] : 0;
      #pragma unroll
      for (int o=1;o<16;o<<=1){ int u = __shfl_up(t,o,64); if (lane >= o) t += u; }
      if (lane < 16) wsum[lane] = t;
    }
    __syncthreads();
    int wexcl = wid ? wsum[wid-1] : 0;
    int incl = x + wexcl;
    int c = carry;
    if (idx < NN) rowp[idx] = c + incl - v;
    __syncthreads();
    if (tid == 1023) carry = c + wsum[15];
    __syncthreads();
  }
  if (threadIdx.x == 0) rowp[NN] = carry;
}

// fill CSR (self loops + edges), compute dinv
__global__ __launch_bounds__(256) void k_fill(const int* __restrict__ src, const int* __restrict__ dst,
                                              const int* __restrict__ rowp, int* __restrict__ cur,
                                              const int* __restrict__ deg, float* __restrict__ dinv,
                                              int* __restrict__ colv){
  int t = blockIdx.x*256 + threadIdx.x;
  if (t < NN){
    dinv[t] = rsqrtf((float)deg[t]);
    int pos = rowp[t] + atomicAdd(&cur[t], 1);
    colv[pos] = t;                       // self loop
  } else if (t < NN + EE){
    int e = t - NN;
    int d = dst[e];
    int pos = rowp[d] + atomicAdd(&cur[d], 1);
    colv[pos] = src[e];
  }
}

// layer-1 GEMM: C[2N x 128] (bf16) = [mask*(X@W1); X@W1], X f32 [N x 128].
// W staged in 64KB LDS; 16 rows/wave, X via wave-uniform loads.
__global__ __launch_bounds__(256) void k_gemm128_l1(const float* __restrict__ X, const float* __restrict__ W,
                                                    const float* __restrict__ mask, ushort_t* __restrict__ C){
  extern __shared__ float Wl[];   // 128*128 floats
  int tid = threadIdx.x;
  #pragma unroll
  for (int i=0;i<16;i++){
    int idx = (i*256 + tid)*4;
    *(float4*)&Wl[idx] = *(const float4*)&W[idx];
  }
  __syncthreads();
  int lane = tid & 63;
  int wid = __builtin_amdgcn_readfirstlane(tid >> 6);
  int row0 = blockIdx.x*64 + wid*16;
  int c2 = lane*2;
  float acc[16][2];
  #pragma unroll
  for (int r=0;r<16;r++){ acc[r][0]=0.f; acc[r][1]=0.f; }
  const float* xp = X + (size_t)row0*FD;
  if (row0 + 16 <= NN){
    #pragma unroll 4
    for (int k=0;k<FD;k++){
      float2 w = *(float2*)&Wl[k*FD + c2];
      #pragma unroll
      for (int r=0;r<16;r++){
        float xv = xp[r*FD + k];
        acc[r][0] += xv*w.x; acc[r][1] += xv*w.y;
      }
    }
  } else {
    int nr = NN - row0; if (nr < 0) nr = 0; if (nr > 16) nr = 16;
    for (int k=0;k<FD;k++){
      float2 w = *(float2*)&Wl[k*FD + c2];
      for (int r=0;r<16;r++){
        if (r < nr){
          float xv = xp[r*FD + k];
          acc[r][0] += xv*w.x; acc[r][1] += xv*w.y;
        }
      }
    }
  }
  #pragma unroll
  for (int r=0;r<16;r++){
    int row = row0 + r;
    if (row < NN){
      float m = mask[row];
      *(uint_t*)&C[(size_t)row*FD + c2]        = pack_bf2(m*acc[r][0], m*acc[r][1]);  // run 0 (masked)
      *(uint_t*)&C[((size_t)NN+row)*FD + c2]   = pack_bf2(acc[r][0], acc[r][1]);      // run 1
    }
  }
}

// GAT-layer GEMM: C[nrows x 128] (bf16) = X(bf16) @ W(f32); fused alpha epilogue:
// asv[row] = row . att_src, adv[row] = row . att_dst
__global__ __launch_bounds__(256) void k_gemm128_g(const ushort_t* __restrict__ X, const float* __restrict__ W,
                                                   const float* __restrict__ avec, const float* __restrict__ bvec,
                                                   ushort_t* __restrict__ C, float* __restrict__ asv,
                                                   float* __restrict__ adv, int nrows){
  extern __shared__ float Wl[];   // 128*128 floats
  int tid = threadIdx.x;
  #pragma unroll
  for (int i=0;i<16;i++){
    int idx = (i*256 + tid)*4;
    *(float4*)&Wl[idx] = *(const float4*)&W[idx];
  }
  __syncthreads();
  int lane = tid & 63;
  int wid = __builtin_amdgcn_readfirstlane(tid >> 6);
  int row0 = blockIdx.x*64 + wid*16;
  int c2 = lane*2;
  float acc[16][2];
  #pragma unroll
  for (int r=0;r<16;r++){ acc[r][0]=0.f; acc[r][1]=0.f; }
  const ushort_t* xp = X + (size_t)row0*FD;
  if (row0 + 16 <= nrows){
    #pragma unroll 4
    for (int k=0;k<FD;k+=2){
      float2 w0 = *(float2*)&Wl[k*FD + c2];
      float2 w1 = *(float2*)&Wl[(k+1)*FD + c2];
      #pragma unroll
      for (int r=0;r<16;r++){
        float2 xv = unpack_bf2(*(const uint_t*)(xp + r*FD + k));
        acc[r][0] += xv.x*w0.x + xv.y*w1.x;
        acc[r][1] += xv.x*w0.y + xv.y*w1.y;
      }
    }
  } else {
    int nr = nrows - row0; if (nr < 0) nr = 0; if (nr > 16) nr = 16;
    for (int k=0;k<FD;k+=2){
      float2 w0 = *(float2*)&Wl[k*FD + c2];
      float2 w1 = *(float2*)&Wl[(k+1)*FD + c2];
      for (int r=0;r<16;r++){
        if (r < nr){
          float2 xv = unpack_bf2(*(const uint_t*)(xp + r*FD + k));
          acc[r][0] += xv.x*w0.x + xv.y*w1.x;
          acc[r][1] += xv.x*w0.y + xv.y*w1.y;
        }
      }
    }
  }
  float2 va = *(const float2*)&avec[c2];
  float2 vb = *(const float2*)&bvec[c2];
  #pragma unroll
  for (int r=0;r<16;r++){
    int row = row0 + r;
    float ps = acc[r][0]*va.x + acc[r][1]*va.y;
    float pd = acc[r][0]*vb.x + acc[r][1]*vb.y;
    ps = wave_red_sum(ps); pd = wave_red_sum(pd);
    if (row < nrows){
      *(uint_t*)&C[(size_t)row*FD + c2] = pack_bf2(acc[r][0], acc[r][1]);
      if (lane == 0){ asv[row] = ps; adv[row] = pd; }
    }
  }
}

// GCN aggregation, both runs fused: wave per dst node
__global__ __launch_bounds__(256) void k_gcn_agg2(const ushort_t* __restrict__ H, const int* __restrict__ rowp,
                                                  const int* __restrict__ colv, const float* __restrict__ dinv,
                                                  const float* __restrict__ bias, ushort_t* __restrict__ O){
  int i = blockIdx.x*4 + (threadIdx.x >> 6);
  int lane = threadIdx.x & 63;
  int c2 = lane*2;
  const ushort_t* H1 = H + (size_t)NN*FD;
  float di = dinv[i];
  float a0x=0.f,a0y=0.f,a1x=0.f,a1y=0.f;
  int e0 = rowp[i], e1 = rowp[i+1];
  int s = colv[e0];
  for (int j=e0; j<e1; j++){
    int snext = (j+1 < e1) ? colv[j+1] : 0;
    float nw = di*dinv[s];
    float2 h0 = unpack_bf2(*(const uint_t*)&H [(size_t)s*FD + c2]);
    float2 h1 = unpack_bf2(*(const uint_t*)&H1[(size_t)s*FD + c2]);
    a0x += nw*h0.x; a0y += nw*h0.y;
    a1x += nw*h1.x; a1y += nw*h1.y;
    s = snext;
  }
  float2 b = *(const float2*)&bias[c2];
  a0x = fmaxf(a0x + b.x, 0.f); a0y = fmaxf(a0y + b.y, 0.f);
  a1x = fmaxf(a1x + b.x, 0.f); a1y = fmaxf(a1y + b.y, 0.f);
  *(uint_t*)&O[(size_t)i*FD + c2]      = pack_bf2(a0x, a0y);
  *(uint_t*)&O[((size_t)NN+i)*FD + c2] = pack_bf2(a1x, a1y);
}

// GAT aggregation, both runs fused: wave per dst node; edge softmax over in-edges
__global__ __launch_bounds__(256) void k_gat_agg2(const ushort_t* __restrict__ H, const int* __restrict__ rowp,
                                                  const int* __restrict__ colv, const float* __restrict__ asv,
                                                  const float* __restrict__ adv, const float* __restrict__ bias,
                                                  ushort_t* __restrict__ O){
  int i = blockIdx.x*4 + (threadIdx.x >> 6);
  int lane = threadIdx.x & 63;
  int c2 = lane*2;
  const ushort_t* H1 = H + (size_t)NN*FD;
  float adi0 = adv[i], adi1 = adv[NN+i];
  int e0 = rowp[i], e1 = rowp[i+1];
  float m0 = -FLT_MAX, m1 = -FLT_MAX;
  for (int j=e0+lane; j<e1; j+=64){
    int s = colv[j];
    float x0 = asv[s]    + adi0; x0 = (x0 > 0.f) ? x0 : 0.2f*x0;
    float x1 = asv[NN+s] + adi1; x1 = (x1 > 0.f) ? x1 : 0.2f*x1;
    m0 = fmaxf(m0, x0); m1 = fmaxf(m1, x1);
  }
  m0 = wave_red_max(m0); m1 = wave_red_max(m1);
  float d0 = 0.f, d1 = 0.f;
  for (int j=e0+lane; j<e1; j+=64){
    int s = colv[j];
    float x0 = asv[s]    + adi0; x0 = (x0 > 0.f) ? x0 : 0.2f*x0;
    float x1 = asv[NN+s] + adi1; x1 = (x1 > 0.f) ? x1 : 0.2f*x1;
    d0 += __expf(x0 - m0); d1 += __expf(x1 - m1);
  }
  d0 = wave_red_sum(d0); d1 = wave_red_sum(d1);
  float inv0 = 1.0f/d0, inv1 = 1.0f/d1;
  float a0x=0.f,a0y=0.f,a1x=0.f,a1y=0.f;
  int s = colv[e0];
  for (int j=e0; j<e1; j++){
    int snext = (j+1 < e1) ? colv[j+1] : 0;
    float x0 = asv[s]    + adi0; x0 = (x0 > 0.f) ? x0 : 0.2f*x0;
    float x1 = asv[NN+s] + adi1; x1 = (x1 > 0.f) ? x1 : 0.2f*x1;
    float w0 = __expf(x0 - m0);
    float w1 = __expf(x1 - m1);
    float2 h0 = unpack_bf2(*(const uint_t*)&H [(size_t)s*FD + c2]);
    float2 h1 = unpack_bf2(*(const uint_t*)&H1[(size_t)s*FD + c2]);
    a0x += w0*h0.x; a0y += w0*h0.y;
    a1x += w1*h1.x; a1y += w1*h1.y;
    s = snext;
  }
  float2 b = *(const float2*)&bias[c2];
  a0x = fmaxf(a0x*inv0 + b.x, 0.f); a0y = fmaxf(a0y*inv0 + b.y, 0.f);
  a1x = fmaxf(a1x*inv1 + b.x, 0.f); a1y = fmaxf(a1y*inv1 + b.y, 0.f);
  *(uint_t*)&O[(size_t)i*FD + c2]      = pack_bf2(a0x, a0y);
  *(uint_t*)&O[((size_t)NN+i)*FD + c2] = pack_bf2(a1x, a1y);
}

// P[ntot x 10] = H(bf16) @ W2 via wave reductions
__global__ __launch_bounds__(256) void k_gemm10(const ushort_t* __restrict__ H, const float* __restrict__ W2,
                                                float* __restrict__ P){
  int w = blockIdx.x*4 + (threadIdx.x >> 6);
  int lane = threadIdx.x & 63;
  float2 h = unpack_bf2(*(const uint_t*)&H[(size_t)w*FD + lane*2]);
  const float* w0 = &W2[(2*lane)*NL];
  const float* w1 = &W2[(2*lane+1)*NL];
  float a[NL];
  #pragma unroll
  for (int l=0;l<NL;l++){
    float p = h.x*w0[l] + h.y*w1[l];
    a[l] = wave_red_sum(p);
  }
  if (lane == 0){
    #pragma unroll
    for (int l=0;l<NL;l++) P[(size_t)w*NL + l] = a[l];
  }
}

// GCN2 aggregation + bias + log_softmax + f32 store
__global__ __launch_bounds__(256) void k_final(const float* __restrict__ P, const int* __restrict__ rowp,
                                               const int* __restrict__ colv, const float* __restrict__ dinv,
                                               const float* __restrict__ b2, float* __restrict__ out){
  int g = blockIdx.x*256 + threadIdx.x;
  if (g >= NTOT) return;
  int r = (g >= NN);
  int i = g - r*NN;
  float di = dinv[i];
  const float* base = P + (size_t)r*NN*NL;
  float acc[NL];
  #pragma unroll
  for (int l=0;l<NL;l++) acc[l] = 0.f;
  int e0 = rowp[i], e1 = rowp[i+1];
  for (int j=e0; j<e1; j++){
    int s = colv[j];
    float nw = di*dinv[s];
    const float* ps = &base[(size_t)s*NL];
    #pragma unroll
    for (int l=0;l<NL;l++) acc[l] += nw*ps[l];
  }
  float mx = -FLT_MAX;
  #pragma unroll
  for (int l=0;l<NL;l++){ acc[l] += b2[l]; mx = fmaxf(mx, acc[l]); }
  float s = 0.f;
  #pragma unroll
  for (int l=0;l<NL;l++) s += __expf(acc[l]-mx);
  float lse = mx + __logf(s);
  #pragma unroll
  for (int l=0;l<NL;l++) out[(size_t)NTOT + (size_t)g*NL + l] = acc[l]-lse;
}

extern "C" void kernel_launch(void* const* d_in, const int* in_sizes, int n_in,
                              void* d_out, int out_size, void* d_ws, size_t ws_size,
                              hipStream_t stream){
  const float* x    = (const float*)d_in[0];
  const int*   ei   = (const int*)  d_in[1];
  const float* dh   = (const float*)d_in[2];
  const float* W1   = (const float*)d_in[3];
  const float* b1   = (const float*)d_in[4];
  const float* Wg   = (const float*)d_in[5];
  const float* asrc = (const float*)d_in[6];
  const float* adst = (const float*)d_in[7];
  const float* bg   = (const float*)d_in[8];
  const float* W2   = (const float*)d_in[9];
  const float* b2   = (const float*)d_in[10];
  float* out = (float*)d_out;

  char* ws = (char*)d_ws;
  size_t off = 0;
  auto alloc = [&](size_t bytes)->void*{ void* p = ws + off; off = (off + bytes + 255) & ~(size_t)255; return p; };
  int*      deg  = (int*)     alloc((size_t)NN*4);
  int*      rowp = (int*)     alloc((size_t)(NN+1)*4);
  int*      cur  = (int*)     alloc((size_t)NN*4);
  float*    dinv = (float*)   alloc((size_t)NN*4);
  float*    mask = (float*)   alloc((size_t)NN*4);
  int*      colv = (int*)     alloc((size_t)(EE+NN)*4);
  ushort_t* bufA = (ushort_t*)alloc((size_t)NTOT*FD*2);
  ushort_t* bufB = (ushort_t*)alloc((size_t)NTOT*FD*2);
  float*    asv  = (float*)   alloc((size_t)NTOT*4);
  float*    adv  = (float*)   alloc((size_t)NTOT*4);
  float*    p10  = (float*)   alloc((size_t)NTOT*NL*4);

  const int* srcp = ei;
  const int* dstp = ei + EE;

  k_prep<<<(NN+255)/256, 256, 0, stream>>>(dh, mask, deg, cur, out);
  k_hist<<<(EE+255)/256, 256, 0, stream>>>(dstp, deg);
  k_scan<<<1, 1024, 0, stream>>>(deg, rowp);
  k_fill<<<(NN+EE+255)/256, 256, 0, stream>>>(srcp, dstp, rowp, cur, deg, dinv, colv);

  // layer 1: GCN  (GEMM on N rows -> bf16 both runs with mask fused)
  k_gemm128_l1<<<(NN+63)/64, 256, 65536, stream>>>(x, W1, mask, bufA);
  k_gcn_agg2<<<NN/4, 256, 0, stream>>>(bufA, rowp, colv, dinv, b1, bufB);

  // layer 2: GAT
  k_gemm128_g<<<(NTOT+63)/64, 256, 65536, stream>>>(bufB, Wg, asrc, adst, bufA, asv, adv, NTOT);
  k_gat_agg2<<<NN/4, 256, 0, stream>>>(bufA, rowp, colv, asv, adv, bg, bufB);

  // layer 3: GAT
  k_gemm128_g<<<(NTOT+63)/64, 256, 65536, stream>>>(bufB, Wg, asrc, adst, bufA, asv, adv, NTOT);
  k_gat_agg2<<<NN/4, 256, 0, stream>>>(bufA, rowp, colv, asv, adv, bg, bufB);

  // layer 4: GCN(128->10) + log_softmax
  k_gemm10<<<NTOT/4, 256, 0, stream>>>(bufB, W2, p10);
  k_final<<<(NTOT+255)/256, 256, 0, stream>>>(p10, rowp, colv, dinv, b2, out);
}

// Round 4
// 578.871 us; speedup vs baseline: 1.8662x; 1.7815x over previous
//
#include <hip/hip_runtime.h>
#include <hip/hip_bf16.h>
#include <cfloat>

#define NN 50000
#define EE 800000
#define FD 128
#define NL 10
#define NTOT 100000   // 2 runs * NN

typedef unsigned short ushort_t;
typedef unsigned int uint_t;
typedef __attribute__((ext_vector_type(8))) __bf16 bf16x8;
typedef __attribute__((ext_vector_type(4))) float f32x4;

__device__ __forceinline__ float wave_red_sum(float v){
  #pragma unroll
  for (int o=1;o<64;o<<=1) v += __shfl_xor(v,o,64);
  return v;
}
__device__ __forceinline__ float wave_red_max(float v){
  #pragma unroll
  for (int o=1;o<64;o<<=1) v = fmaxf(v,__shfl_xor(v,o,64));
  return v;
}
__device__ __forceinline__ float red16_sum(float v){
  #pragma unroll
  for (int o=1;o<16;o<<=1) v += __shfl_xor(v,o,64);
  return v;
}

// bf16 helpers (RTNE pack, bit unpack)
__device__ __forceinline__ ushort_t f2bf(float f){
  uint_t i = __float_as_uint(f);
  uint_t r = i + 0x7fffu + ((i>>16)&1u);
  return (ushort_t)(r>>16);
}
__device__ __forceinline__ uint_t pack_bf2(float x, float y){
  return (uint_t)f2bf(x) | ((uint_t)f2bf(y)<<16);
}
__device__ __forceinline__ float2 unpack_bf2(uint_t v){
  float2 r;
  r.x = __uint_as_float((v & 0xffffu) << 16);
  r.y = __uint_as_float(v & 0xffff0000u);
  return r;
}

// drop mask, drop_b output (f32), deg/cursor init
__global__ __launch_bounds__(256) void k_prep(const float* __restrict__ dh, float* __restrict__ mask,
                                              int* __restrict__ deg, int* __restrict__ cur,
                                              float* __restrict__ out){
  int i = blockIdx.x*256 + threadIdx.x;
  if (i >= NN) return;
  float m = (dh[i] + dh[NN+i] + dh[2*NN+i] + dh[3*NN+i]) * 0.25f;
  bool dropped = (m != 0.0f);
  mask[i] = dropped ? 0.0f : 1.0f;
  deg[i] = 1;            // self loop
  cur[i] = 0;
  out[i]      = dropped ? 1.0f : 0.0f;  // run 0 drop_b
  out[NN + i] = 0.0f;                   // run 1 drop_b (bernoulli p=0)
}

__global__ __launch_bounds__(256) void k_hist(const int* __restrict__ dst, int* __restrict__ deg){
  int e = blockIdx.x*256 + threadIdx.x;
  if (e < EE) atomicAdd(&deg[dst[e]], 1);
}

// exclusive scan of deg -> rowp, single block of 1024
__global__ __launch_bounds__(1024) void k_scan(const int* __restrict__ deg, int* __restrict__ rowp){
  __shared__ int wsum[16];
  __shared__ int carry;
  int tid = threadIdx.x, lane = tid & 63, wid = tid >> 6;
  if (tid == 0) carry = 0;
  __syncthreads();
  for (int base = 0; base < NN; base += 1024){
    int idx = base + tid;
    int v = (idx < NN) ? deg[idx] : 0;
    int x = v;
    #pragma unroll
    for (int o=1;o<64;o<<=1){ int t = __shfl_up(x,o,64); if (lane >= o) x += t; }
    if (lane == 63) wsum[wid] = x;
    __syncthreads();
    if (wid == 0){
      int t = (lane < 16) ? wsum[lane] : 0;
      #pragma unroll
      for (int o=1;o<16;o<<=1){ int u = __shfl_up(t,o,64); if (lane >= o) t += u; }
      if (lane < 16) wsum[lane] = t;
    }
    __syncthreads();
    int wexcl = wid ? wsum[wid-1] : 0;
    int incl = x + wexcl;
    int c = carry;
    if (idx < NN) rowp[idx] = c + incl - v;
    __syncthreads();
    if (tid == 1023) carry = c + wsum[15];
    __syncthreads();
  }
  if (threadIdx.x == 0) rowp[NN] = carry;
}

// fill CSR (self loops + edges), compute dinv
__global__ __launch_bounds__(256) void k_fill(const int* __restrict__ src, const int* __restrict__ dst,
                                              const int* __restrict__ rowp, int* __restrict__ cur,
                                              const int* __restrict__ deg, float* __restrict__ dinv,
                                              int* __restrict__ colv){
  int t = blockIdx.x*256 + threadIdx.x;
  if (t < NN){
    dinv[t] = rsqrtf((float)deg[t]);
    int pos = rowp[t] + atomicAdd(&cur[t], 1);
    colv[pos] = t;                       // self loop
  } else if (t < NN + EE){
    int e = t - NN;
    int d = dst[e];
    int pos = rowp[d] + atomicAdd(&cur[d], 1);
    colv[pos] = src[e];
  }
}

// one-time: transpose weights to [n][k] bf16 (W2 padded to 16 cols)
__global__ __launch_bounds__(256) void k_wprep(const float* __restrict__ W1, const float* __restrict__ Wg,
                                               const float* __restrict__ W2, ushort_t* __restrict__ Wt1,
                                               ushort_t* __restrict__ Wtg, ushort_t* __restrict__ Wt2){
  int e = blockIdx.x*256 + threadIdx.x;
  if (e < 16384){ int k=e>>7, n=e&127; Wt1[n*128+k] = f2bf(W1[e]); }
  else if (e < 32768){ int e2=e-16384; int k=e2>>7, n=e2&127; Wtg[n*128+k] = f2bf(Wg[e2]); }
  else if (e < 32768+2048){ int e2=e-32768; int n=e2>>7, k=e2&127; Wt2[n*128+k] = (n<NL)? f2bf(W2[k*NL+n]) : (ushort_t)0; }
}

// X f32 -> bf16
__global__ __launch_bounds__(256) void k_xbf(const float* __restrict__ X, ushort_t* __restrict__ Y){
  int i = blockIdx.x*256 + threadIdx.x;   // float4 index
  if (i >= NN*FD/4) return;
  float4 v = *(const float4*)&X[(size_t)i*4];
  uint2 p; p.x = pack_bf2(v.x,v.y); p.y = pack_bf2(v.z,v.w);
  *(uint2*)&Y[(size_t)i*4] = p;
}

// stage Wt [nrows x 128] bf16 into LDS with XOR swizzle (byte ^= (row&7)<<4)
__device__ __forceinline__ void stage_w(const ushort_t* __restrict__ Wt, ushort_t* lds, int nchunks){
  for (int c = threadIdx.x; c < nchunks; c += 256){
    int row = c >> 4;
    int cb  = (c & 15) * 16;
    int dst = row*256 + (cb ^ ((row & 7) << 4));
    *(float4*)((char*)lds + dst) = *(const float4*)&Wt[(size_t)c*8];
  }
}
__device__ __forceinline__ bf16x8 read_b(const ushort_t* lds, int ncol, int kstep, int g){
  int byte = ncol*256 + ((kstep*64 + g*16) ^ ((ncol & 7) << 4));
  return *(const bf16x8*)((const char*)lds + byte);
}

// MFMA GEMM layer1: C[2N x 128] bf16 = [mask*(X@W1); X@W1]
__global__ __launch_bounds__(256) void k_mm_l1(const ushort_t* __restrict__ X, const ushort_t* __restrict__ Wt,
                                               const float* __restrict__ mask, ushort_t* __restrict__ C){
  __shared__ ushort_t Wl[128*128];
  stage_w(Wt, Wl, 2048);
  __syncthreads();
  int lane = threadIdx.x & 63, wid = threadIdx.x >> 6;
  int row0 = (blockIdx.x*4 + wid)*16;
  if (row0 + 16 > NN) return;
  int r16 = lane & 15, g = lane >> 4;
  const ushort_t* ap = X + (size_t)(row0 + r16)*FD + g*8;
  bf16x8 a[4];
  #pragma unroll
  for (int t=0;t<4;t++) a[t] = *(const bf16x8*)(ap + t*32);
  f32x4 acc[8];
  #pragma unroll
  for (int nt=0;nt<8;nt++){
    f32x4 c = {0.f,0.f,0.f,0.f};
    #pragma unroll
    for (int t=0;t<4;t++)
      c = __builtin_amdgcn_mfma_f32_16x16x32_bf16(a[t], read_b(Wl, nt*16 + r16, t, g), c, 0,0,0);
    acc[nt] = c;
  }
  float mk[4];
  #pragma unroll
  for (int r=0;r<4;r++) mk[r] = mask[row0 + g*4 + r];
  #pragma unroll
  for (int nt=0;nt<8;nt++){
    int col = nt*16 + r16;
    #pragma unroll
    for (int r=0;r<4;r++){
      int row = row0 + g*4 + r;
      C[(size_t)row*FD + col]            = f2bf(mk[r]*acc[nt][r]);
      C[((size_t)NN + row)*FD + col]     = f2bf(acc[nt][r]);
    }
  }
}

// MFMA GEMM GAT layer: C bf16 = X@Wg, fused asv/adv epilogue
__global__ __launch_bounds__(256) void k_mm_g(const ushort_t* __restrict__ X, const ushort_t* __restrict__ Wt,
                                              const float* __restrict__ avec, const float* __restrict__ bvec,
                                              ushort_t* __restrict__ C, float* __restrict__ asv,
                                              float* __restrict__ adv, int nrows){
  __shared__ ushort_t Wl[128*128];
  stage_w(Wt, Wl, 2048);
  __syncthreads();
  int lane = threadIdx.x & 63, wid = threadIdx.x >> 6;
  int row0 = (blockIdx.x*4 + wid)*16;
  if (row0 + 16 > nrows) return;
  int r16 = lane & 15, g = lane >> 4;
  const ushort_t* ap = X + (size_t)(row0 + r16)*FD + g*8;
  bf16x8 a[4];
  #pragma unroll
  for (int t=0;t<4;t++) a[t] = *(const bf16x8*)(ap + t*32);
  f32x4 acc[8];
  #pragma unroll
  for (int nt=0;nt<8;nt++){
    f32x4 c = {0.f,0.f,0.f,0.f};
    #pragma unroll
    for (int t=0;t<4;t++)
      c = __builtin_amdgcn_mfma_f32_16x16x32_bf16(a[t], read_b(Wl, nt*16 + r16, t, g), c, 0,0,0);
    acc[nt] = c;
  }
  float av[8], bv[8];
  #pragma unroll
  for (int nt=0;nt<8;nt++){ av[nt] = avec[nt*16 + r16]; bv[nt] = bvec[nt*16 + r16]; }
  #pragma unroll
  for (int r=0;r<4;r++){
    float sa = 0.f, sd = 0.f;
    #pragma unroll
    for (int nt=0;nt<8;nt++){ sa += acc[nt][r]*av[nt]; sd += acc[nt][r]*bv[nt]; }
    sa = red16_sum(sa); sd = red16_sum(sd);
    if (r16 == 0){
      int row = row0 + g*4 + r;
      asv[row] = sa; adv[row] = sd;
    }
  }
  #pragma unroll
  for (int nt=0;nt<8;nt++){
    int col = nt*16 + r16;
    #pragma unroll
    for (int r=0;r<4;r++)
      C[(size_t)(row0 + g*4 + r)*FD + col] = f2bf(acc[nt][r]);
  }
}

// MFMA 128->16(10): P[ntot x 10] f32
__global__ __launch_bounds__(256) void k_mm10(const ushort_t* __restrict__ X, const ushort_t* __restrict__ Wt2,
                                              float* __restrict__ P){
  __shared__ ushort_t Wl[16*128];
  stage_w(Wt2, Wl, 256);
  __syncthreads();
  int lane = threadIdx.x & 63, wid = threadIdx.x >> 6;
  int row0 = (blockIdx.x*4 + wid)*16;
  if (row0 + 16 > NTOT) return;
  int r16 = lane & 15, g = lane >> 4;
  const ushort_t* ap = X + (size_t)(row0 + r16)*FD + g*8;
  f32x4 c = {0.f,0.f,0.f,0.f};
  #pragma unroll
  for (int t=0;t<4;t++){
    bf16x8 a = *(const bf16x8*)(ap + t*32);
    c = __builtin_amdgcn_mfma_f32_16x16x32_bf16(a, read_b(Wl, r16, t, g), c, 0,0,0);
  }
  if (r16 < NL){
    #pragma unroll
    for (int r=0;r<4;r++) P[(size_t)(row0 + g*4 + r)*NL + r16] = c[r];
  }
}

// GCN aggregation, both runs fused: wave per dst node
__global__ __launch_bounds__(256) void k_gcn_agg2(const ushort_t* __restrict__ H, const int* __restrict__ rowp,
                                                  const int* __restrict__ colv, const float* __restrict__ dinv,
                                                  const float* __restrict__ bias, ushort_t* __restrict__ O){
  int i = blockIdx.x*4 + (threadIdx.x >> 6);
  int lane = threadIdx.x & 63;
  int c2 = lane*2;
  const ushort_t* H1 = H + (size_t)NN*FD;
  float di = dinv[i];
  float a0x=0.f,a0y=0.f,a1x=0.f,a1y=0.f;
  int e0 = rowp[i], e1 = rowp[i+1];
  int s = colv[e0];
  for (int j=e0; j<e1; j++){
    int snext = (j+1 < e1) ? colv[j+1] : 0;
    float nw = di*dinv[s];
    float2 h0 = unpack_bf2(*(const uint_t*)&H [(size_t)s*FD + c2]);
    float2 h1 = unpack_bf2(*(const uint_t*)&H1[(size_t)s*FD + c2]);
    a0x += nw*h0.x; a0y += nw*h0.y;
    a1x += nw*h1.x; a1y += nw*h1.y;
    s = snext;
  }
  float2 b = *(const float2*)&bias[c2];
  a0x = fmaxf(a0x + b.x, 0.f); a0y = fmaxf(a0y + b.y, 0.f);
  a1x = fmaxf(a1x + b.x, 0.f); a1y = fmaxf(a1y + b.y, 0.f);
  *(uint_t*)&O[(size_t)i*FD + c2]      = pack_bf2(a0x, a0y);
  *(uint_t*)&O[((size_t)NN+i)*FD + c2] = pack_bf2(a1x, a1y);
}

// GAT aggregation, both runs fused: wave per dst node; edge softmax over in-edges
__global__ __launch_bounds__(256) void k_gat_agg2(const ushort_t* __restrict__ H, const int* __restrict__ rowp,
                                                  const int* __restrict__ colv, const float* __restrict__ asv,
                                                  const float* __restrict__ adv, const float* __restrict__ bias,
                                                  ushort_t* __restrict__ O){
  int i = blockIdx.x*4 + (threadIdx.x >> 6);
  int lane = threadIdx.x & 63;
  int c2 = lane*2;
  const ushort_t* H1 = H + (size_t)NN*FD;
  float adi0 = adv[i], adi1 = adv[NN+i];
  int e0 = rowp[i], e1 = rowp[i+1];
  float m0 = -FLT_MAX, m1 = -FLT_MAX;
  for (int j=e0+lane; j<e1; j+=64){
    int s = colv[j];
    float x0 = asv[s]    + adi0; x0 = (x0 > 0.f) ? x0 : 0.2f*x0;
    float x1 = asv[NN+s] + adi1; x1 = (x1 > 0.f) ? x1 : 0.2f*x1;
    m0 = fmaxf(m0, x0); m1 = fmaxf(m1, x1);
  }
  m0 = wave_red_max(m0); m1 = wave_red_max(m1);
  float d0 = 0.f, d1 = 0.f;
  for (int j=e0+lane; j<e1; j+=64){
    int s = colv[j];
    float x0 = asv[s]    + adi0; x0 = (x0 > 0.f) ? x0 : 0.2f*x0;
    float x1 = asv[NN+s] + adi1; x1 = (x1 > 0.f) ? x1 : 0.2f*x1;
    d0 += __expf(x0 - m0); d1 += __expf(x1 - m1);
  }
  d0 = wave_red_sum(d0); d1 = wave_red_sum(d1);
  float inv0 = 1.0f/d0, inv1 = 1.0f/d1;
  float a0x=0.f,a0y=0.f,a1x=0.f,a1y=0.f;
  int s = colv[e0];
  for (int j=e0; j<e1; j++){
    int snext = (j+1 < e1) ? colv[j+1] : 0;
    float x0 = asv[s]    + adi0; x0 = (x0 > 0.f) ? x0 : 0.2f*x0;
    float x1 = asv[NN+s] + adi1; x1 = (x1 > 0.f) ? x1 : 0.2f*x1;
    float w0 = __expf(x0 - m0);
    float w1 = __expf(x1 - m1);
    float2 h0 = unpack_bf2(*(const uint_t*)&H [(size_t)s*FD + c2]);
    float2 h1 = unpack_bf2(*(const uint_t*)&H1[(size_t)s*FD + c2]);
    a0x += w0*h0.x; a0y += w0*h0.y;
    a1x += w1*h1.x; a1y += w1*h1.y;
    s = snext;
  }
  float2 b = *(const float2*)&bias[c2];
  a0x = fmaxf(a0x*inv0 + b.x, 0.f); a0y = fmaxf(a0y*inv0 + b.y, 0.f);
  a1x = fmaxf(a1x*inv1 + b.x, 0.f); a1y = fmaxf(a1y*inv1 + b.y, 0.f);
  *(uint_t*)&O[(size_t)i*FD + c2]      = pack_bf2(a0x, a0y);
  *(uint_t*)&O[((size_t)NN+i)*FD + c2] = pack_bf2(a1x, a1y);
}

// GCN2 aggregation + bias + log_softmax + f32 store
__global__ __launch_bounds__(256) void k_final(const float* __restrict__ P, const int* __restrict__ rowp,
                                               const int* __restrict__ colv, const float* __restrict__ dinv,
                                               const float* __restrict__ b2, float* __restrict__ out){
  int g = blockIdx.x*256 + threadIdx.x;
  if (g >= NTOT) return;
  int r = (g >= NN);
  int i = g - r*NN;
  float di = dinv[i];
  const float* base = P + (size_t)r*NN*NL;
  float acc[NL];
  #pragma unroll
  for (int l=0;l<NL;l++) acc[l] = 0.f;
  int e0 = rowp[i], e1 = rowp[i+1];
  for (int j=e0; j<e1; j++){
    int s = colv[j];
    float nw = di*dinv[s];
    const float* ps = &base[(size_t)s*NL];
    #pragma unroll
    for (int l=0;l<NL;l++) acc[l] += nw*ps[l];
  }
  float mx = -FLT_MAX;
  #pragma unroll
  for (int l=0;l<NL;l++){ acc[l] += b2[l]; mx = fmaxf(mx, acc[l]); }
  float s = 0.f;
  #pragma unroll
  for (int l=0;l<NL;l++) s += __expf(acc[l]-mx);
  float lse = mx + __logf(s);
  #pragma unroll
  for (int l=0;l<NL;l++) out[(size_t)NTOT + (size_t)g*NL + l] = acc[l]-lse;
}

extern "C" void kernel_launch(void* const* d_in, const int* in_sizes, int n_in,
                              void* d_out, int out_size, void* d_ws, size_t ws_size,
                              hipStream_t stream){
  const float* x    = (const float*)d_in[0];
  const int*   ei   = (const int*)  d_in[1];
  const float* dh   = (const float*)d_in[2];
  const float* W1   = (const float*)d_in[3];
  const float* b1   = (const float*)d_in[4];
  const float* Wg   = (const float*)d_in[5];
  const float* asrc = (const float*)d_in[6];
  const float* adst = (const float*)d_in[7];
  const float* bg   = (const float*)d_in[8];
  const float* W2   = (const float*)d_in[9];
  const float* b2   = (const float*)d_in[10];
  float* out = (float*)d_out;

  char* ws = (char*)d_ws;
  size_t off = 0;
  auto alloc = [&](size_t bytes)->void*{ void* p = ws + off; off = (off + bytes + 255) & ~(size_t)255; return p; };
  int*      deg  = (int*)     alloc((size_t)NN*4);
  int*      rowp = (int*)     alloc((size_t)(NN+1)*4);
  int*      cur  = (int*)     alloc((size_t)NN*4);
  float*    dinv = (float*)   alloc((size_t)NN*4);
  float*    mask = (float*)   alloc((size_t)NN*4);
  int*      colv = (int*)     alloc((size_t)(EE+NN)*4);
  ushort_t* bufA = (ushort_t*)alloc((size_t)NTOT*FD*2);
  ushort_t* bufB = (ushort_t*)alloc((size_t)NTOT*FD*2);
  float*    asv  = (float*)   alloc((size_t)NTOT*4);
  float*    adv  = (float*)   alloc((size_t)NTOT*4);
  float*    p10  = (float*)   alloc((size_t)NTOT*NL*4);
  ushort_t* xbf  = (ushort_t*)alloc((size_t)NN*FD*2);
  ushort_t* Wt1  = (ushort_t*)alloc((size_t)128*128*2);
  ushort_t* Wtg  = (ushort_t*)alloc((size_t)128*128*2);
  ushort_t* Wt2  = (ushort_t*)alloc((size_t)16*128*2);

  const int* srcp = ei;
  const int* dstp = ei + EE;

  k_prep<<<(NN+255)/256, 256, 0, stream>>>(dh, mask, deg, cur, out);
  k_hist<<<(EE+255)/256, 256, 0, stream>>>(dstp, deg);
  k_scan<<<1, 1024, 0, stream>>>(deg, rowp);
  k_fill<<<(NN+EE+255)/256, 256, 0, stream>>>(srcp, dstp, rowp, cur, deg, dinv, colv);
  k_wprep<<<136, 256, 0, stream>>>(W1, Wg, W2, Wt1, Wtg, Wt2);
  k_xbf<<<(NN*FD/4+255)/256, 256, 0, stream>>>(x, xbf);

  // layer 1: GCN
  k_mm_l1<<<(NN+63)/64, 256, 0, stream>>>(xbf, Wt1, mask, bufA);
  k_gcn_agg2<<<NN/4, 256, 0, stream>>>(bufA, rowp, colv, dinv, b1, bufB);

  // layer 2: GAT
  k_mm_g<<<(NTOT+63)/64, 256, 0, stream>>>(bufB, Wtg, asrc, adst, bufA, asv, adv, NTOT);
  k_gat_agg2<<<NN/4, 256, 0, stream>>>(bufA, rowp, colv, asv, adv, bg, bufB);

  // layer 3: GAT
  k_mm_g<<<(NTOT+63)/64, 256, 0, stream>>>(bufB, Wtg, asrc, adst, bufA, asv, adv, NTOT);
  k_gat_agg2<<<NN/4, 256, 0, stream>>>(bufA, rowp, colv, asv, adv, bg, bufB);

  // layer 4: GCN(128->10) + log_softmax
  k_mm10<<<(NTOT+63)/64, 256, 0, stream>>>(bufB, Wt2, p10);
  k_final<<<(NTOT+255)/256, 256, 0, stream>>>(p10, rowp, colv, dinv, b2, out);
}

// Round 5
// 424.229 us; speedup vs baseline: 2.5465x; 1.3645x over previous
//
#include <hip/hip_runtime.h>
#include <hip/hip_bf16.h>
#include <cfloat>

#define NN 50000
#define EE 800000
#define FD 128
#define NL 10
#define NTOT 100000   // 2 runs * NN

typedef unsigned short ushort_t;
typedef unsigned int uint_t;
typedef __attribute__((ext_vector_type(8))) __bf16 bf16x8;
typedef __attribute__((ext_vector_type(4))) float f32x4;

__device__ __forceinline__ float wave_red_sum(float v){
  #pragma unroll
  for (int o=1;o<64;o<<=1) v += __shfl_xor(v,o,64);
  return v;
}
__device__ __forceinline__ float wave_red_max(float v){
  #pragma unroll
  for (int o=1;o<64;o<<=1) v = fmaxf(v,__shfl_xor(v,o,64));
  return v;
}
__device__ __forceinline__ float red16_sum(float v){
  #pragma unroll
  for (int o=1;o<16;o<<=1) v += __shfl_xor(v,o,64);
  return v;
}

// bf16 helpers (RTNE pack, bit unpack)
__device__ __forceinline__ ushort_t f2bf(float f){
  uint_t i = __float_as_uint(f);
  uint_t r = i + 0x7fffu + ((i>>16)&1u);
  return (ushort_t)(r>>16);
}
__device__ __forceinline__ uint_t pack_bf2(float x, float y){
  return (uint_t)f2bf(x) | ((uint_t)f2bf(y)<<16);
}

// drop mask, drop_b output (f32), deg/cursor init
__global__ __launch_bounds__(256) void k_prep(const float* __restrict__ dh, float* __restrict__ mask,
                                              int* __restrict__ deg, int* __restrict__ cur,
                                              float* __restrict__ out){
  int i = blockIdx.x*256 + threadIdx.x;
  if (i >= NN) return;
  float m = (dh[i] + dh[NN+i] + dh[2*NN+i] + dh[3*NN+i]) * 0.25f;
  bool dropped = (m != 0.0f);
  mask[i] = dropped ? 0.0f : 1.0f;
  deg[i] = 1;            // self loop
  cur[i] = 0;
  out[i]      = dropped ? 1.0f : 0.0f;  // run 0 drop_b
  out[NN + i] = 0.0f;                   // run 1 drop_b (bernoulli p=0)
}

__global__ __launch_bounds__(256) void k_hist(const int* __restrict__ dst, int* __restrict__ deg){
  int e = blockIdx.x*256 + threadIdx.x;
  if (e < EE) atomicAdd(&deg[dst[e]], 1);
}

// exclusive scan of deg -> rowp, single block of 1024
__global__ __launch_bounds__(1024) void k_scan(const int* __restrict__ deg, int* __restrict__ rowp){
  __shared__ int wsum[16];
  __shared__ int carry;
  int tid = threadIdx.x, lane = tid & 63, wid = tid >> 6;
  if (tid == 0) carry = 0;
  __syncthreads();
  for (int base = 0; base < NN; base += 1024){
    int idx = base + tid;
    int v = (idx < NN) ? deg[idx] : 0;
    int x = v;
    #pragma unroll
    for (int o=1;o<64;o<<=1){ int t = __shfl_up(x,o,64); if (lane >= o) x += t; }
    if (lane == 63) wsum[wid] = x;
    __syncthreads();
    if (wid == 0){
      int t = (lane < 16) ? wsum[lane] : 0;
      #pragma unroll
      for (int o=1;o<16;o<<=1){ int u = __shfl_up(t,o,64); if (lane >= o) t += u; }
      if (lane < 16) wsum[lane] = t;
    }
    __syncthreads();
    int wexcl = wid ? wsum[wid-1] : 0;
    int incl = x + wexcl;
    int c = carry;
    if (idx < NN) rowp[idx] = c + incl - v;
    __syncthreads();
    if (tid == 1023) carry = c + wsum[15];
    __syncthreads();
  }
  if (threadIdx.x == 0) rowp[NN] = carry;
}

// fill CSR (self loops + edges), compute dinv
__global__ __launch_bounds__(256) void k_fill(const int* __restrict__ src, const int* __restrict__ dst,
                                              const int* __restrict__ rowp, int* __restrict__ cur,
                                              const int* __restrict__ deg, float* __restrict__ dinv,
                                              int* __restrict__ colv){
  int t = blockIdx.x*256 + threadIdx.x;
  if (t < NN){
    dinv[t] = rsqrtf((float)deg[t]);
    int pos = rowp[t] + atomicAdd(&cur[t], 1);
    colv[pos] = t;                       // self loop
  } else if (t < NN + EE){
    int e = t - NN;
    int d = dst[e];
    int pos = rowp[d] + atomicAdd(&cur[d], 1);
    colv[pos] = src[e];
  }
}

// one-time: transpose weights to [n][k] bf16 (W2 padded to 16 cols)
__global__ __launch_bounds__(256) void k_wprep(const float* __restrict__ W1, const float* __restrict__ Wg,
                                               const float* __restrict__ W2, ushort_t* __restrict__ Wt1,
                                               ushort_t* __restrict__ Wtg, ushort_t* __restrict__ Wt2){
  int e = blockIdx.x*256 + threadIdx.x;
  if (e < 16384){ int k=e>>7, n=e&127; Wt1[n*128+k] = f2bf(W1[e]); }
  else if (e < 32768){ int e2=e-16384; int k=e2>>7, n=e2&127; Wtg[n*128+k] = f2bf(Wg[e2]); }
  else if (e < 32768+2048){ int e2=e-32768; int n=e2>>7, k=e2&127; Wt2[n*128+k] = (n<NL)? f2bf(W2[k*NL+n]) : (ushort_t)0; }
}

// X f32 -> bf16
__global__ __launch_bounds__(256) void k_xbf(const float* __restrict__ X, ushort_t* __restrict__ Y){
  int i = blockIdx.x*256 + threadIdx.x;   // float4 index
  if (i >= NN*FD/4) return;
  float4 v = *(const float4*)&X[(size_t)i*4];
  uint2 p; p.x = pack_bf2(v.x,v.y); p.y = pack_bf2(v.z,v.w);
  *(uint2*)&Y[(size_t)i*4] = p;
}

// stage Wt [nrows x 128] bf16 into LDS with XOR swizzle (byte ^= (row&7)<<4)
__device__ __forceinline__ void stage_w(const ushort_t* __restrict__ Wt, ushort_t* lds, int nchunks){
  for (int c = threadIdx.x; c < nchunks; c += 256){
    int row = c >> 4;
    int cb  = (c & 15) * 16;
    int dst = row*256 + (cb ^ ((row & 7) << 4));
    *(float4*)((char*)lds + dst) = *(const float4*)&Wt[(size_t)c*8];
  }
}
__device__ __forceinline__ bf16x8 read_b(const ushort_t* lds, int ncol, int kstep, int g){
  int byte = ncol*256 + ((kstep*64 + g*16) ^ ((ncol & 7) << 4));
  return *(const bf16x8*)((const char*)lds + byte);
}

// MFMA GEMM layer1: C[2N x 128] bf16 = [mask*(X@W1); X@W1]
__global__ __launch_bounds__(256) void k_mm_l1(const ushort_t* __restrict__ X, const ushort_t* __restrict__ Wt,
                                               const float* __restrict__ mask, ushort_t* __restrict__ C){
  __shared__ ushort_t Wl[128*128];
  stage_w(Wt, Wl, 2048);
  __syncthreads();
  int lane = threadIdx.x & 63, wid = threadIdx.x >> 6;
  int row0 = (blockIdx.x*4 + wid)*16;
  if (row0 + 16 > NN) return;
  int r16 = lane & 15, g = lane >> 4;
  const ushort_t* ap = X + (size_t)(row0 + r16)*FD + g*8;
  bf16x8 a[4];
  #pragma unroll
  for (int t=0;t<4;t++) a[t] = *(const bf16x8*)(ap + t*32);
  f32x4 acc[8];
  #pragma unroll
  for (int nt=0;nt<8;nt++){
    f32x4 c = {0.f,0.f,0.f,0.f};
    #pragma unroll
    for (int t=0;t<4;t++)
      c = __builtin_amdgcn_mfma_f32_16x16x32_bf16(a[t], read_b(Wl, nt*16 + r16, t, g), c, 0,0,0);
    acc[nt] = c;
  }
  float mk[4];
  #pragma unroll
  for (int r=0;r<4;r++) mk[r] = mask[row0 + g*4 + r];
  #pragma unroll
  for (int nt=0;nt<8;nt++){
    int col = nt*16 + r16;
    #pragma unroll
    for (int r=0;r<4;r++){
      int row = row0 + g*4 + r;
      C[(size_t)row*FD + col]            = f2bf(mk[r]*acc[nt][r]);
      C[((size_t)NN + row)*FD + col]     = f2bf(acc[nt][r]);
    }
  }
}

// MFMA GEMM GAT layer: C bf16 = X@Wg, fused asv/adv epilogue
__global__ __launch_bounds__(256) void k_mm_g(const ushort_t* __restrict__ X, const ushort_t* __restrict__ Wt,
                                              const float* __restrict__ avec, const float* __restrict__ bvec,
                                              ushort_t* __restrict__ C, float* __restrict__ asv,
                                              float* __restrict__ adv, int nrows){
  __shared__ ushort_t Wl[128*128];
  stage_w(Wt, Wl, 2048);
  __syncthreads();
  int lane = threadIdx.x & 63, wid = threadIdx.x >> 6;
  int row0 = (blockIdx.x*4 + wid)*16;
  if (row0 + 16 > nrows) return;
  int r16 = lane & 15, g = lane >> 4;
  const ushort_t* ap = X + (size_t)(row0 + r16)*FD + g*8;
  bf16x8 a[4];
  #pragma unroll
  for (int t=0;t<4;t++) a[t] = *(const bf16x8*)(ap + t*32);
  f32x4 acc[8];
  #pragma unroll
  for (int nt=0;nt<8;nt++){
    f32x4 c = {0.f,0.f,0.f,0.f};
    #pragma unroll
    for (int t=0;t<4;t++)
      c = __builtin_amdgcn_mfma_f32_16x16x32_bf16(a[t], read_b(Wl, nt*16 + r16, t, g), c, 0,0,0);
    acc[nt] = c;
  }
  float av[8], bv[8];
  #pragma unroll
  for (int nt=0;nt<8;nt++){ av[nt] = avec[nt*16 + r16]; bv[nt] = bvec[nt*16 + r16]; }
  #pragma unroll
  for (int r=0;r<4;r++){
    float sa = 0.f, sd = 0.f;
    #pragma unroll
    for (int nt=0;nt<8;nt++){ sa += acc[nt][r]*av[nt]; sd += acc[nt][r]*bv[nt]; }
    sa = red16_sum(sa); sd = red16_sum(sd);
    if (r16 == 0){
      int row = row0 + g*4 + r;
      asv[row] = sa; adv[row] = sd;
    }
  }
  #pragma unroll
  for (int nt=0;nt<8;nt++){
    int col = nt*16 + r16;
    #pragma unroll
    for (int r=0;r<4;r++)
      C[(size_t)(row0 + g*4 + r)*FD + col] = f2bf(acc[nt][r]);
  }
}

// MFMA 128->16(10): P[ntot x 10] f32
__global__ __launch_bounds__(256) void k_mm10(const ushort_t* __restrict__ X, const ushort_t* __restrict__ Wt2,
                                              float* __restrict__ P){
  __shared__ ushort_t Wl[16*128];
  stage_w(Wt2, Wl, 256);
  __syncthreads();
  int lane = threadIdx.x & 63, wid = threadIdx.x >> 6;
  int row0 = (blockIdx.x*4 + wid)*16;
  if (row0 + 16 > NTOT) return;
  int r16 = lane & 15, g = lane >> 4;
  const ushort_t* ap = X + (size_t)(row0 + r16)*FD + g*8;
  f32x4 c = {0.f,0.f,0.f,0.f};
  #pragma unroll
  for (int t=0;t<4;t++){
    bf16x8 a = *(const bf16x8*)(ap + t*32);
    c = __builtin_amdgcn_mfma_f32_16x16x32_bf16(a, read_b(Wl, r16, t, g), c, 0,0,0);
  }
  if (r16 < NL){
    #pragma unroll
    for (int r=0;r<4;r++) P[(size_t)(row0 + g*4 + r)*NL + r16] = c[r];
  }
}

// GCN aggregation v3: wave/node, 4 edge-groups x 16 lanes (bf16x8 per lane)
__global__ __launch_bounds__(256) void k_gcn_agg3(const ushort_t* __restrict__ H, const int* __restrict__ rowp,
                                                  const int* __restrict__ colv, const float* __restrict__ dinv,
                                                  const float* __restrict__ bias, ushort_t* __restrict__ O){
  int i = blockIdx.x*4 + (threadIdx.x >> 6);
  int lane = threadIdx.x & 63;
  int eg = lane >> 4, f = lane & 15;
  const ushort_t* H1 = H + (size_t)NN*FD;
  float di = dinv[i];
  int e0 = rowp[i], e1 = rowp[i+1];
  float a0[8], a1[8];
  #pragma unroll
  for (int t=0;t<8;t++){ a0[t]=0.f; a1[t]=0.f; }
  for (int j0=e0; j0<e1; j0+=4){
    int je = j0 + eg;
    bool ok = je < e1;
    int s = ok ? colv[je] : 0;
    float nw = ok ? di*dinv[s] : 0.f;
    bf16x8 h0 = *(const bf16x8*)&H [(size_t)s*FD + f*8];
    bf16x8 h1 = *(const bf16x8*)&H1[(size_t)s*FD + f*8];
    #pragma unroll
    for (int t=0;t<8;t++){
      a0[t] += nw*(float)h0[t];
      a1[t] += nw*(float)h1[t];
    }
  }
  #pragma unroll
  for (int t=0;t<8;t++){
    a0[t] += __shfl_xor(a0[t],16,64); a0[t] += __shfl_xor(a0[t],32,64);
    a1[t] += __shfl_xor(a1[t],16,64); a1[t] += __shfl_xor(a1[t],32,64);
  }
  float4 b0 = *(const float4*)&bias[f*8];
  float4 b1 = *(const float4*)&bias[f*8+4];
  float bb[8] = {b0.x,b0.y,b0.z,b0.w,b1.x,b1.y,b1.z,b1.w};
  if (eg == 0){
    uint4 p;
    p.x = pack_bf2(fmaxf(a0[0]+bb[0],0.f), fmaxf(a0[1]+bb[1],0.f));
    p.y = pack_bf2(fmaxf(a0[2]+bb[2],0.f), fmaxf(a0[3]+bb[3],0.f));
    p.z = pack_bf2(fmaxf(a0[4]+bb[4],0.f), fmaxf(a0[5]+bb[5],0.f));
    p.w = pack_bf2(fmaxf(a0[6]+bb[6],0.f), fmaxf(a0[7]+bb[7],0.f));
    *(uint4*)&O[(size_t)i*FD + f*8] = p;
  } else if (eg == 1){
    uint4 p;
    p.x = pack_bf2(fmaxf(a1[0]+bb[0],0.f), fmaxf(a1[1]+bb[1],0.f));
    p.y = pack_bf2(fmaxf(a1[2]+bb[2],0.f), fmaxf(a1[3]+bb[3],0.f));
    p.z = pack_bf2(fmaxf(a1[4]+bb[4],0.f), fmaxf(a1[5]+bb[5],0.f));
    p.w = pack_bf2(fmaxf(a1[6]+bb[6],0.f), fmaxf(a1[7]+bb[7],0.f));
    *(uint4*)&O[((size_t)NN+i)*FD + f*8] = p;
  }
}

// GAT aggregation v3: wave/node, 4 edge-groups x 16 lanes; denom fused into agg pass
__global__ __launch_bounds__(256) void k_gat_agg3(const ushort_t* __restrict__ H, const int* __restrict__ rowp,
                                                  const int* __restrict__ colv, const float* __restrict__ asv,
                                                  const float* __restrict__ adv, const float* __restrict__ bias,
                                                  ushort_t* __restrict__ O){
  int i = blockIdx.x*4 + (threadIdx.x >> 6);
  int lane = threadIdx.x & 63;
  int eg = lane >> 4, f = lane & 15;
  const ushort_t* H1 = H + (size_t)NN*FD;
  float adi0 = adv[i], adi1 = adv[NN+i];
  int e0 = rowp[i], e1 = rowp[i+1];
  // pass 1: max over in-edges (lane-parallel)
  float m0 = -FLT_MAX, m1 = -FLT_MAX;
  for (int j=e0+lane; j<e1; j+=64){
    int s = colv[j];
    float x0 = asv[s]    + adi0; x0 = (x0 > 0.f) ? x0 : 0.2f*x0;
    float x1 = asv[NN+s] + adi1; x1 = (x1 > 0.f) ? x1 : 0.2f*x1;
    m0 = fmaxf(m0, x0); m1 = fmaxf(m1, x1);
  }
  m0 = wave_red_max(m0); m1 = wave_red_max(m1);
  // pass 2: fused weighted aggregation + denominator
  float a0[8], a1[8];
  #pragma unroll
  for (int t=0;t<8;t++){ a0[t]=0.f; a1[t]=0.f; }
  float d0 = 0.f, d1 = 0.f;
  for (int j0=e0; j0<e1; j0+=4){
    int je = j0 + eg;
    bool ok = je < e1;
    int s = ok ? colv[je] : 0;
    float w0 = 0.f, w1 = 0.f;
    if (ok){
      float x0 = asv[s]    + adi0; x0 = (x0 > 0.f) ? x0 : 0.2f*x0;
      float x1 = asv[NN+s] + adi1; x1 = (x1 > 0.f) ? x1 : 0.2f*x1;
      w0 = __expf(x0 - m0); w1 = __expf(x1 - m1);
    }
    d0 += w0; d1 += w1;
    bf16x8 h0 = *(const bf16x8*)&H [(size_t)s*FD + f*8];
    bf16x8 h1 = *(const bf16x8*)&H1[(size_t)s*FD + f*8];
    #pragma unroll
    for (int t=0;t<8;t++){
      a0[t] += w0*(float)h0[t];
      a1[t] += w1*(float)h1[t];
    }
  }
  #pragma unroll
  for (int t=0;t<8;t++){
    a0[t] += __shfl_xor(a0[t],16,64); a0[t] += __shfl_xor(a0[t],32,64);
    a1[t] += __shfl_xor(a1[t],16,64); a1[t] += __shfl_xor(a1[t],32,64);
  }
  d0 += __shfl_xor(d0,16,64); d0 += __shfl_xor(d0,32,64);
  d1 += __shfl_xor(d1,16,64); d1 += __shfl_xor(d1,32,64);
  float inv0 = 1.0f/d0, inv1 = 1.0f/d1;
  float4 b0 = *(const float4*)&bias[f*8];
  float4 b1 = *(const float4*)&bias[f*8+4];
  float bb[8] = {b0.x,b0.y,b0.z,b0.w,b1.x,b1.y,b1.z,b1.w};
  if (eg == 0){
    uint4 p;
    p.x = pack_bf2(fmaxf(a0[0]*inv0+bb[0],0.f), fmaxf(a0[1]*inv0+bb[1],0.f));
    p.y = pack_bf2(fmaxf(a0[2]*inv0+bb[2],0.f), fmaxf(a0[3]*inv0+bb[3],0.f));
    p.z = pack_bf2(fmaxf(a0[4]*inv0+bb[4],0.f), fmaxf(a0[5]*inv0+bb[5],0.f));
    p.w = pack_bf2(fmaxf(a0[6]*inv0+bb[6],0.f), fmaxf(a0[7]*inv0+bb[7],0.f));
    *(uint4*)&O[(size_t)i*FD + f*8] = p;
  } else if (eg == 1){
    uint4 p;
    p.x = pack_bf2(fmaxf(a1[0]*inv1+bb[0],0.f), fmaxf(a1[1]*inv1+bb[1],0.f));
    p.y = pack_bf2(fmaxf(a1[2]*inv1+bb[2],0.f), fmaxf(a1[3]*inv1+bb[3],0.f));
    p.z = pack_bf2(fmaxf(a1[4]*inv1+bb[4],0.f), fmaxf(a1[5]*inv1+bb[5],0.f));
    p.w = pack_bf2(fmaxf(a1[6]*inv1+bb[6],0.f), fmaxf(a1[7]*inv1+bb[7],0.f));
    *(uint4*)&O[((size_t)NN+i)*FD + f*8] = p;
  }
}

// GCN2 agg + log_softmax v2: wave per 4 nodes, 16 edge-parallel lanes per node
__global__ __launch_bounds__(256) void k_final2(const float* __restrict__ P, const int* __restrict__ rowp,
                                                const int* __restrict__ colv, const float* __restrict__ dinv,
                                                const float* __restrict__ b2, float* __restrict__ out){
  int wid = threadIdx.x >> 6, lane = threadIdx.x & 63;
  int ng = lane >> 4, le = lane & 15;
  int gi = (blockIdx.x*4 + wid)*4 + ng;
  int r = (gi >= NN);
  int i = gi - r*NN;
  float di = dinv[i];
  const float* base = P + (size_t)r*NN*NL;
  float acc[NL];
  #pragma unroll
  for (int l=0;l<NL;l++) acc[l] = 0.f;
  int e0 = rowp[i], e1 = rowp[i+1];
  for (int j0=e0; j0<e1; j0+=16){
    int je = j0 + le;
    bool ok = je < e1;
    int s = ok ? colv[je] : 0;
    float nw = ok ? di*dinv[s] : 0.f;
    const float* ps = &base[(size_t)s*NL];
    #pragma unroll
    for (int l=0;l<NL;l++) acc[l] += nw*ps[l];
  }
  #pragma unroll
  for (int l=0;l<NL;l++){
    acc[l] += __shfl_xor(acc[l],1,64);
    acc[l] += __shfl_xor(acc[l],2,64);
    acc[l] += __shfl_xor(acc[l],4,64);
    acc[l] += __shfl_xor(acc[l],8,64);
  }
  if (le == 0){
    float mx = -FLT_MAX;
    #pragma unroll
    for (int l=0;l<NL;l++){ acc[l] += b2[l]; mx = fmaxf(mx, acc[l]); }
    float s = 0.f;
    #pragma unroll
    for (int l=0;l<NL;l++) s += __expf(acc[l]-mx);
    float lse = mx + __logf(s);
    #pragma unroll
    for (int l=0;l<NL;l++) out[(size_t)NTOT + (size_t)gi*NL + l] = acc[l]-lse;
  }
}

extern "C" void kernel_launch(void* const* d_in, const int* in_sizes, int n_in,
                              void* d_out, int out_size, void* d_ws, size_t ws_size,
                              hipStream_t stream){
  const float* x    = (const float*)d_in[0];
  const int*   ei   = (const int*)  d_in[1];
  const float* dh   = (const float*)d_in[2];
  const float* W1   = (const float*)d_in[3];
  const float* b1   = (const float*)d_in[4];
  const float* Wg   = (const float*)d_in[5];
  const float* asrc = (const float*)d_in[6];
  const float* adst = (const float*)d_in[7];
  const float* bg   = (const float*)d_in[8];
  const float* W2   = (const float*)d_in[9];
  const float* b2   = (const float*)d_in[10];
  float* out = (float*)d_out;

  char* ws = (char*)d_ws;
  size_t off = 0;
  auto alloc = [&](size_t bytes)->void*{ void* p = ws + off; off = (off + bytes + 255) & ~(size_t)255; return p; };
  int*      deg  = (int*)     alloc((size_t)NN*4);
  int*      rowp = (int*)     alloc((size_t)(NN+1)*4);
  int*      cur  = (int*)     alloc((size_t)NN*4);
  float*    dinv = (float*)   alloc((size_t)NN*4);
  float*    mask = (float*)   alloc((size_t)NN*4);
  int*      colv = (int*)     alloc((size_t)(EE+NN)*4);
  ushort_t* bufA = (ushort_t*)alloc((size_t)NTOT*FD*2);
  ushort_t* bufB = (ushort_t*)alloc((size_t)NTOT*FD*2);
  float*    asv  = (float*)   alloc((size_t)NTOT*4);
  float*    adv  = (float*)   alloc((size_t)NTOT*4);
  float*    p10  = (float*)   alloc((size_t)NTOT*NL*4);
  ushort_t* xbf  = (ushort_t*)alloc((size_t)NN*FD*2);
  ushort_t* Wt1  = (ushort_t*)alloc((size_t)128*128*2);
  ushort_t* Wtg  = (ushort_t*)alloc((size_t)128*128*2);
  ushort_t* Wt2  = (ushort_t*)alloc((size_t)16*128*2);

  const int* srcp = ei;
  const int* dstp = ei + EE;

  k_prep<<<(NN+255)/256, 256, 0, stream>>>(dh, mask, deg, cur, out);
  k_hist<<<(EE+255)/256, 256, 0, stream>>>(dstp, deg);
  k_scan<<<1, 1024, 0, stream>>>(deg, rowp);
  k_fill<<<(NN+EE+255)/256, 256, 0, stream>>>(srcp, dstp, rowp, cur, deg, dinv, colv);
  k_wprep<<<136, 256, 0, stream>>>(W1, Wg, W2, Wt1, Wtg, Wt2);
  k_xbf<<<(NN*FD/4+255)/256, 256, 0, stream>>>(x, xbf);

  // layer 1: GCN
  k_mm_l1<<<(NN+63)/64, 256, 0, stream>>>(xbf, Wt1, mask, bufA);
  k_gcn_agg3<<<NN/4, 256, 0, stream>>>(bufA, rowp, colv, dinv, b1, bufB);

  // layer 2: GAT
  k_mm_g<<<(NTOT+63)/64, 256, 0, stream>>>(bufB, Wtg, asrc, adst, bufA, asv, adv, NTOT);
  k_gat_agg3<<<NN/4, 256, 0, stream>>>(bufA, rowp, colv, asv, adv, bg, bufB);

  // layer 3: GAT
  k_mm_g<<<(NTOT+63)/64, 256, 0, stream>>>(bufB, Wtg, asrc, adst, bufA, asv, adv, NTOT);
  k_gat_agg3<<<NN/4, 256, 0, stream>>>(bufA, rowp, colv, asv, adv, bg, bufB);

  // layer 4: GCN(128->10) + log_softmax
  k_mm10<<<(NTOT+63)/64, 256, 0, stream>>>(bufB, Wt2, p10);
  k_final2<<<(NTOT+15)/16, 256, 0, stream>>>(p10, rowp, colv, dinv, b2, out);
}